// Round 7
// baseline (26.556 us; speedup 1.0000x reference)
//
#include <hip/hip_runtime.h>

// y[row] = (sum over elements e>=1 of W[e-1]) / (count of elements >=1) + b
// rna_data: (B, S) int32 in [0, 64]; W: 64 floats; b: scalar; out: (B,) f32.
//
// Two rows per 64-lane wave, 4 waves (8 rows) per block, grid = B/8.
// - All 16 NT int4 loads (2 rows) issued up-front: 256 B/lane in flight,
//   row A's reduction overlaps row B's loads; halves block generations.
// - wave-private W2[65] table (W2[0]=0), no block barrier
// - branchless gather; count via ballot+popcount (scalar pipe)
// - shuffle reduction for sum only

typedef int int4v __attribute__((ext_vector_type(4)));

template<int NV>   // int4 loads per row (S / 256)
__global__ __launch_bounds__(256) void codon_rows2_kernel(
    const int* __restrict__ rna,
    const float* __restrict__ W,
    const float* __restrict__ b,
    float* __restrict__ out,
    int S)
{
    const int t    = threadIdx.x;
    const int wave = t >> 6;
    const int lane = t & 63;
    const int rowA = blockIdx.x * 8 + wave * 2;
    const int rowB = rowA + 1;

    // 1) Issue BOTH rows' loads immediately (16 outstanding 16B NT loads/lane).
    const int4v* pA = reinterpret_cast<const int4v*>(rna + (size_t)rowA * (size_t)S);
    const int4v* pB = reinterpret_cast<const int4v*>(rna + (size_t)rowB * (size_t)S);
    int4v vA[NV], vB[NV];
    #pragma unroll
    for (int k = 0; k < NV; ++k)
        vA[k] = __builtin_nontemporal_load(&pA[lane + 64 * k]);
    #pragma unroll
    for (int k = 0; k < NV; ++k)
        vB[k] = __builtin_nontemporal_load(&pB[lane + 64 * k]);

    // 2) Wave-private extended table (no block barrier; in-wave DS ordering).
    __shared__ float W2[4][65];
    W2[wave][lane + 1] = W[lane];
    if (lane == 0) W2[wave][0] = 0.0f;
    const float* Wl = W2[wave];
    const float bv = b[0];

    // 3) Row A: gather + accumulate (overlaps row B's in-flight loads).
    float sumA = 0.0f;
    int   cntA = 0;
    #pragma unroll
    for (int k = 0; k < NV; ++k) {
        #pragma unroll
        for (int j = 0; j < 4; ++j) {
            int e = vA[k][j];
            sumA += Wl[e];
            cntA += (int)__popcll(__ballot(e > 0));
        }
    }
    #pragma unroll
    for (int off = 32; off > 0; off >>= 1)
        sumA += __shfl_down(sumA, off, 64);
    if (lane == 0)
        out[rowA] = sumA / (float)cntA + bv;

    // 4) Row B.
    float sumB = 0.0f;
    int   cntB = 0;
    #pragma unroll
    for (int k = 0; k < NV; ++k) {
        #pragma unroll
        for (int j = 0; j < 4; ++j) {
            int e = vB[k][j];
            sumB += Wl[e];
            cntB += (int)__popcll(__ballot(e > 0));
        }
    }
    #pragma unroll
    for (int off = 32; off > 0; off >>= 1)
        sumB += __shfl_down(sumB, off, 64);
    if (lane == 0)
        out[rowB] = sumB / (float)cntB + bv;
}

// Generic fallback (any S, any B): one block per row, runtime loop.
__global__ __launch_bounds__(256) void codon_freq_dot_kernel(
    const int* __restrict__ rna,
    const float* __restrict__ W,
    const float* __restrict__ b,
    float* __restrict__ out,
    int S)
{
    __shared__ float Wl[64];
    __shared__ float psum[4];
    __shared__ int   pcnt[4];

    const int row = blockIdx.x;
    const int t   = threadIdx.x;

    if (t < 64) Wl[t] = W[t];
    __syncthreads();

    const int* base = rna + (size_t)row * (size_t)S;

    float sum = 0.0f;
    int   cnt = 0;

    for (int i = t; i < S; i += 256) {
        int e = base[i];
        if (e > 0) { sum += Wl[e - 1]; ++cnt; }
    }

    #pragma unroll
    for (int off = 32; off > 0; off >>= 1) {
        sum += __shfl_down(sum, off, 64);
        cnt += __shfl_down(cnt, off, 64);
    }

    const int wave = t >> 6;
    const int lane = t & 63;
    if (lane == 0) { psum[wave] = sum; pcnt[wave] = cnt; }
    __syncthreads();

    if (t == 0) {
        float s = psum[0] + psum[1] + psum[2] + psum[3];
        int   c = pcnt[0] + pcnt[1] + pcnt[2] + pcnt[3];
        out[row] = s / (float)c + b[0];
    }
}

extern "C" void kernel_launch(void* const* d_in, const int* in_sizes, int n_in,
                              void* d_out, int out_size, void* d_ws, size_t ws_size,
                              hipStream_t stream) {
    const int*   rna = (const int*)d_in[0];
    // d_in[1] = tissue_id -- unused by the reference computation
    const float* W   = (const float*)d_in[2];
    const float* b   = (const float*)d_in[3];
    float*       out = (float*)d_out;

    const int B = out_size;              // 16384 rows (output is (B,1))
    const int S = in_sizes[0] / B;       // 2048 codons per row

    if (S == 2048 && (B & 7) == 0) {
        // 2 rows per wave, 8 rows per block
        codon_rows2_kernel<8><<<B / 8, 256, 0, stream>>>(rna, W, b, out, S);
    } else {
        codon_freq_dot_kernel<<<B, 256, 0, stream>>>(rna, W, b, out, S);
    }
}

// Round 8
// 24.506 us; speedup vs baseline: 1.0836x; 1.0836x over previous
//
#include <hip/hip_runtime.h>

// y[row] = (sum over elements e>=1 of W[e-1]) / (count of elements >=1) + b
// rna_data: (B, S) int32 in [0, 64]; W: 64 floats; b: scalar; out: (B,) f32.
//
// One 64-lane wave per row, 4 rows per 256-thread block.  (R5 best: 23.80 us)
// - NT int4 loads (plain cached loads regressed: R4)
// - branchless gather via extended table W2[65] (W2[0]=0)
// - nonzero count on the SCALAR pipe via ballot+popcount (wave-uniform)
// - shuffle reduction for sum only
// Rejected by measurement: 2 rows/wave (R7, VGPR/occupancy cost), wave-private
// W2 without barrier (R6, neutral), plain cached loads (R4, -7%).

typedef int int4v __attribute__((ext_vector_type(4)));

template<int NV>
__global__ __launch_bounds__(256) void codon_rows_kernel(
    const int* __restrict__ rna,
    const float* __restrict__ W,
    const float* __restrict__ b,
    float* __restrict__ out,
    int S)
{
    __shared__ float W2[65];   // W2[0]=0, W2[e]=W[e-1]
    const int t = threadIdx.x;
    if (t == 0) W2[0] = 0.0f;
    if (t < 64) W2[t + 1] = W[t];
    __syncthreads();

    const int wave = t >> 6;
    const int lane = t & 63;
    const int row  = blockIdx.x * 4 + wave;

    const int4v* p = reinterpret_cast<const int4v*>(rna + (size_t)row * (size_t)S);

    int4v v[NV];
    #pragma unroll
    for (int k = 0; k < NV; ++k)
        v[k] = __builtin_nontemporal_load(&p[lane + 64 * k]);

    float sum = 0.0f;
    int   cnt = 0;   // wave-uniform (ballot/popcount)
    #pragma unroll
    for (int k = 0; k < NV; ++k) {
        #pragma unroll
        for (int j = 0; j < 4; ++j) {
            int e = v[k][j];
            sum += W2[e];                                   // branchless gather
            cnt += (int)__popcll(__ballot(e > 0));          // SALU count
        }
    }

    // 64-lane wave reduction, sum only (cnt already wave-uniform)
    #pragma unroll
    for (int off = 32; off > 0; off >>= 1)
        sum += __shfl_down(sum, off, 64);

    if (lane == 0)
        out[row] = sum / (float)cnt + b[0];
}

// Generic fallback (any S, any B): one block per row, runtime loop.
__global__ __launch_bounds__(256) void codon_freq_dot_kernel(
    const int* __restrict__ rna,
    const float* __restrict__ W,
    const float* __restrict__ b,
    float* __restrict__ out,
    int S)
{
    __shared__ float Wl[64];
    __shared__ float psum[4];
    __shared__ int   pcnt[4];

    const int row = blockIdx.x;
    const int t   = threadIdx.x;

    if (t < 64) Wl[t] = W[t];
    __syncthreads();

    const int* base = rna + (size_t)row * (size_t)S;

    float sum = 0.0f;
    int   cnt = 0;

    for (int i = t; i < S; i += 256) {
        int e = base[i];
        if (e > 0) { sum += Wl[e - 1]; ++cnt; }
    }

    #pragma unroll
    for (int off = 32; off > 0; off >>= 1) {
        sum += __shfl_down(sum, off, 64);
        cnt += __shfl_down(cnt, off, 64);
    }

    const int wave = t >> 6;
    const int lane = t & 63;
    if (lane == 0) { psum[wave] = sum; pcnt[wave] = cnt; }
    __syncthreads();

    if (t == 0) {
        float s = psum[0] + psum[1] + psum[2] + psum[3];
        int   c = pcnt[0] + pcnt[1] + pcnt[2] + pcnt[3];
        out[row] = s / (float)c + b[0];
    }
}

extern "C" void kernel_launch(void* const* d_in, const int* in_sizes, int n_in,
                              void* d_out, int out_size, void* d_ws, size_t ws_size,
                              hipStream_t stream) {
    const int*   rna = (const int*)d_in[0];
    // d_in[1] = tissue_id -- unused by the reference computation
    const float* W   = (const float*)d_in[2];
    const float* b   = (const float*)d_in[3];
    float*       out = (float*)d_out;

    const int B = out_size;              // 16384 rows (output is (B,1))
    const int S = in_sizes[0] / B;       // 2048 codons per row

    if (S == 2048 && (B & 3) == 0) {
        // 8 int4 per lane, 1 wave per row, 4 rows per block
        codon_rows_kernel<8><<<B / 4, 256, 0, stream>>>(rna, W, b, out, S);
    } else {
        codon_freq_dot_kernel<<<B, 256, 0, stream>>>(rna, W, b, out, S);
    }
}